// Round 1
// baseline (77.633 us; speedup 1.0000x reference)
//
#include <hip/hip_runtime.h>
#include <math.h>

// Router: logits = X @ W^T + b ; top-2 over experts; softmax over the 2; rest 0.
// X: [32768, 1024] fp32, W: [64, 1024] fp32, b: [64] fp32, Out: [32768, 64] fp32.
//
// Layout: 512 blocks x 256 threads. Each block: 64 tokens, all 64 experts.
// Split-K: wave q handles d in [q*256, (q+1)*256). Each wave stages its own
// LDS tiles (no barriers in main loop). Per-thread 8x8 register tile:
// lane -> (tg = lane>>3 token group, eg = lane&7 expert group).

#define TPB 64         // tokens per block
#define DK  16         // d-chunk per staging iteration
#define DPQ 256        // d per quarter (1024/4)
#define NCHUNK (DPQ / DK)

__launch_bounds__(256, 2)
__global__ void router_kernel(const float* __restrict__ X,
                              const float* __restrict__ W,
                              const float* __restrict__ Bv,
                              float* __restrict__ Out)
{
    // +1 pad => compute reads are <=2-way bank conflicts (free).
    __shared__ __align__(16) float sIn[4][TPB][DK + 1];
    __shared__ __align__(16) float sW [4][64][DK + 1];
    __shared__ float sB[64];
    __shared__ float sScr[3][64][33];   // quarter-reduction scratch (32 accs/round)
    __shared__ float rW1[TPB], rW2[TPB];
    __shared__ int   rI1[TPB], rI2[TPB];

    const int tid  = threadIdx.x;
    const int q    = tid >> 6;       // wave id = K-quarter
    const int lane = tid & 63;
    const int tg   = lane >> 3;      // token group (8 tokens)
    const int eg   = lane & 7;       // expert group (8 experts)
    const int tokBase = blockIdx.x * TPB;

    if (tid < 64) sB[tid] = Bv[tid];

    // Staging roles: lane -> (row st = lane>>2 in 0..15, float4 col sc = lane&3)
    const int st = lane >> 2;
    const int sc = lane & 3;
    const int dq0 = q * DPQ;

    const float* pIn = X + (size_t)(tokBase + st) * 1024 + dq0 + sc * 4;
    const float* pW  = W + (size_t)st * 1024 + dq0 + sc * 4;

    float acc[8][8];
    #pragma unroll
    for (int i = 0; i < 8; ++i)
        #pragma unroll
        for (int j = 0; j < 8; ++j) acc[i][j] = 0.f;

    float4 bufA[8], bufB[8];

    auto LOAD = [&](int c, float4* buf) {
        const int off = c * DK;
        #pragma unroll
        for (int k = 0; k < 4; ++k) {
            buf[k]     = *(const float4*)(pIn + (size_t)k * 16 * 1024 + off);
            buf[4 + k] = *(const float4*)(pW  + (size_t)k * 16 * 1024 + off);
        }
    };
    auto STORE = [&](const float4* buf) {
        #pragma unroll
        for (int k = 0; k < 4; ++k) {
            const int r = st + k * 16;
            sIn[q][r][sc * 4 + 0] = buf[k].x;
            sIn[q][r][sc * 4 + 1] = buf[k].y;
            sIn[q][r][sc * 4 + 2] = buf[k].z;
            sIn[q][r][sc * 4 + 3] = buf[k].w;
            sW [q][r][sc * 4 + 0] = buf[4 + k].x;
            sW [q][r][sc * 4 + 1] = buf[4 + k].y;
            sW [q][r][sc * 4 + 2] = buf[4 + k].z;
            sW [q][r][sc * 4 + 3] = buf[4 + k].w;
        }
    };
    auto COMPUTE = [&]() {
        #pragma unroll 4
        for (int dd = 0; dd < DK; ++dd) {
            float av[8], wv[8];
            #pragma unroll
            for (int i = 0; i < 8; ++i) av[i] = sIn[q][tg * 8 + i][dd];
            #pragma unroll
            for (int j = 0; j < 8; ++j) wv[j] = sW[q][eg * 8 + j][dd];
            #pragma unroll
            for (int i = 0; i < 8; ++i)
                #pragma unroll
                for (int j = 0; j < 8; ++j)
                    acc[i][j] = fmaf(av[i], wv[j], acc[i][j]);
        }
    };

    // Main loop: wave-private LDS tiles, manual 2-chunk pipeline.
    LOAD(0, bufA);
    #pragma unroll 1
    for (int c = 0; c < NCHUNK; c += 2) {
        STORE(bufA);
        if (c + 1 < NCHUNK) LOAD(c + 1, bufB);
        COMPUTE();
        STORE(bufB);
        if (c + 2 < NCHUNK) LOAD(c + 2, bufA);
        COMPUTE();
    }

    // ---- Cross-quarter reduction (2 rounds of 32 accs through padded LDS) ----
    __syncthreads();
    if (q > 0) {
        #pragma unroll
        for (int i = 0; i < 4; ++i)
            #pragma unroll
            for (int j = 0; j < 8; ++j)
                sScr[q - 1][lane][i * 8 + j] = acc[i][j];
    }
    __syncthreads();
    if (q == 0) {
        #pragma unroll
        for (int qq = 0; qq < 3; ++qq)
            #pragma unroll
            for (int i = 0; i < 4; ++i)
                #pragma unroll
                for (int j = 0; j < 8; ++j)
                    acc[i][j] += sScr[qq][lane][i * 8 + j];
    }
    __syncthreads();
    if (q > 0) {
        #pragma unroll
        for (int i = 4; i < 8; ++i)
            #pragma unroll
            for (int j = 0; j < 8; ++j)
                sScr[q - 1][lane][(i - 4) * 8 + j] = acc[i][j];
    }
    __syncthreads();
    if (q == 0) {
        #pragma unroll
        for (int qq = 0; qq < 3; ++qq)
            #pragma unroll
            for (int i = 4; i < 8; ++i)
                #pragma unroll
                for (int j = 0; j < 8; ++j)
                    acc[i][j] += sScr[qq][lane][(i - 4) * 8 + j];

        // ---- Top-2 + softmax. Wave 0 holds full logits:
        // lane (tg,eg) has logits[8tg+i][8eg+j] in acc[i][j].
        float bj[8];
        #pragma unroll
        for (int j = 0; j < 8; ++j) bj[j] = sB[eg * 8 + j];

        #pragma unroll
        for (int i = 0; i < 8; ++i) {
            float v1 = -INFINITY, v2 = -INFINITY;
            int i1 = 0, i2 = 0;
            #pragma unroll
            for (int j = 0; j < 8; ++j) {
                const float v = acc[i][j] + bj[j];
                const int   e = eg * 8 + j;
                if (v > v1)      { v2 = v1; i2 = i1; v1 = v; i1 = e; }
                else if (v > v2) { v2 = v;  i2 = e; }
            }
            // Butterfly merge across the 8 eg-lanes (lex order: value desc, idx asc
            // == jax top_k stable tie semantics).
            #pragma unroll
            for (int s = 1; s <= 4; s <<= 1) {
                const float o1 = __shfl_xor(v1, s);
                const int  oi1 = __shfl_xor(i1, s);
                const float o2 = __shfl_xor(v2, s);
                const int  oi2 = __shfl_xor(i2, s);
                const bool b1 = (o1 > v1) || (o1 == v1 && oi1 < i1);
                if (b1) {
                    const bool b2 = (v1 > o2) || (v1 == o2 && i1 < oi2);
                    v2 = b2 ? v1 : o2;  i2 = b2 ? i1 : oi2;
                    v1 = o1;            i1 = oi1;
                } else {
                    const bool b2 = (o1 > v2) || (o1 == v2 && oi1 < i2);
                    if (b2) { v2 = o1; i2 = oi1; }
                }
            }
            if (eg == i) {
                const float e2 = expf(v2 - v1);       // <= 1
                const float w1 = 1.f / (1.f + e2);
                rI1[tg * 8 + i] = i1;
                rI2[tg * 8 + i] = i2;
                rW1[tg * 8 + i] = w1;
                rW2[tg * 8 + i] = e2 * w1;
            }
        }
    }
    __syncthreads();

    // ---- Coalesced output: 64 tokens x 64 floats = 1024 float4, contiguous ----
    float4* O4 = (float4*)(Out + (size_t)tokBase * 64);
    #pragma unroll
    for (int idx = tid; idx < TPB * 64 / 4; idx += 256) {
        const int t  = idx >> 4;
        const int e0 = (idx & 15) << 2;
        const int i1 = rI1[t], i2 = rI2[t];
        const float w1 = rW1[t], w2 = rW2[t];
        float4 o;
        o.x = (e0 + 0 == i1) ? w1 : ((e0 + 0 == i2) ? w2 : 0.f);
        o.y = (e0 + 1 == i1) ? w1 : ((e0 + 1 == i2) ? w2 : 0.f);
        o.z = (e0 + 2 == i1) ? w1 : ((e0 + 2 == i2) ? w2 : 0.f);
        o.w = (e0 + 3 == i1) ? w1 : ((e0 + 3 == i2) ? w2 : 0.f);
        O4[idx] = o;
    }
}

extern "C" void kernel_launch(void* const* d_in, const int* in_sizes, int n_in,
                              void* d_out, int out_size, void* d_ws, size_t ws_size,
                              hipStream_t stream) {
    const float* X  = (const float*)d_in[0];   // [8*4096, 1024]
    const float* Wt = (const float*)d_in[1];   // [64, 1024]
    const float* Bv = (const float*)d_in[2];   // [64]
    float* Out = (float*)d_out;                // [8*4096, 64]

    const int tokens = 8 * 4096;               // 32768
    dim3 grid(tokens / TPB);                   // 512 blocks
    dim3 block(256);
    hipLaunchKernelGGL(router_kernel, grid, block, 0, stream, X, Wt, Bv, Out);
}